// Round 1
// 481.357 us; speedup vs baseline: 1.0055x; 1.0055x over previous
//
#include <hip/hip_runtime.h>
#include <hip/hip_bf16.h>
#include <stdint.h>
#include <stddef.h>

#define B_ 4
#define N_ 1024
#define C_ 384
#define H_ 6
#define D_ 64
#define TC_ 1152          // 3*C
#define BHNN_ 25165824    // B*H*N*N
#define SCALE 0.125f
#define LOG2E 1.4426950408889634f
#define LN2 0.6931471805599453f

typedef __hip_bfloat16 bf16;
typedef __attribute__((ext_vector_type(4))) float f32x4;
typedef __attribute__((ext_vector_type(8))) short short8;

__device__ __forceinline__ short f2bs(float x){
  bf16 b = __float2bfloat16(x);
  return *reinterpret_cast<short*>(&b);
}

// ---------------- Threefry-2x32 (matches jax._src.prng) ----------------
#define TFR(x0,x1,r) { x0 += x1; x1 = ((x1)<<(r))|((x1)>>(32-(r))); x1 ^= x0; }

__host__ __device__ __forceinline__ void tf2x32(uint32_t k0, uint32_t k1,
                                                uint32_t& x0, uint32_t& x1){
  uint32_t k2 = k0 ^ k1 ^ 0x1BD11BDAu;
  x0 += k0; x1 += k1;
  TFR(x0,x1,13) TFR(x0,x1,15) TFR(x0,x1,26) TFR(x0,x1,6)
  x0 += k1; x1 += k2 + 1u;
  TFR(x0,x1,17) TFR(x0,x1,29) TFR(x0,x1,16) TFR(x0,x1,24)
  x0 += k2; x1 += k0 + 2u;
  TFR(x0,x1,13) TFR(x0,x1,15) TFR(x0,x1,26) TFR(x0,x1,6)
  x0 += k0; x1 += k1 + 3u;
  TFR(x0,x1,17) TFR(x0,x1,29) TFR(x0,x1,16) TFR(x0,x1,24)
  x0 += k1; x1 += k2 + 4u;
  TFR(x0,x1,13) TFR(x0,x1,15) TFR(x0,x1,26) TFR(x0,x1,6)
  x0 += k2; x1 += k0 + 5u;
}

// single-op rotate: v_alignbit_b32(x, x, 32-r) == rotl(x, r)
__device__ __forceinline__ uint32_t rotl32(uint32_t x, uint32_t r){
#if __has_builtin(__builtin_amdgcn_alignbit)
  return __builtin_amdgcn_alignbit(x, x, 32u - r);
#else
  return (x << r) | (x >> (32u - r));
#endif
}

// dual-stream threefry: computes uniforms for BOTH gumbel keys at counter (0, j),
// manually interleaved for 2-way ILP through the serial round chain.
__device__ __forceinline__ void tf_dual(uint32_t j,
    uint32_t ak0, uint32_t ak1, uint32_t ak2,
    uint32_t bk0, uint32_t bk1, uint32_t bk2,
    float& fA, float& fB){
  uint32_t x0 = ak0, x1 = j + ak1;      // x{0,1} start at (0, j); round-0 key inject folded
  uint32_t y0 = bk0, y1 = j + bk1;
  #define DTFR(r) { x0 += x1; y0 += y1;               \
                    x1 = rotl32(x1,(r)); y1 = rotl32(y1,(r)); \
                    x1 ^= x0; y1 ^= y0; }
  DTFR(13) DTFR(15) DTFR(26) DTFR(6)
  x0 += ak1; x1 += ak2 + 1u;  y0 += bk1; y1 += bk2 + 1u;
  DTFR(17) DTFR(29) DTFR(16) DTFR(24)
  x0 += ak2; x1 += ak0 + 2u;  y0 += bk2; y1 += bk0 + 2u;
  DTFR(13) DTFR(15) DTFR(26) DTFR(6)
  x0 += ak0; x1 += ak1 + 3u;  y0 += bk0; y1 += bk1 + 3u;
  DTFR(17) DTFR(29) DTFR(16) DTFR(24)
  x0 += ak1; x1 += ak2 + 4u;  y0 += bk1; y1 += bk2 + 4u;
  DTFR(13) DTFR(15) DTFR(26) DTFR(6)
  x0 += ak2; x1 += ak0 + 5u;  y0 += bk2; y1 += bk0 + 5u;
  #undef DTFR
  uint32_t bitsA = x0 ^ x1;
  uint32_t bitsB = y0 ^ y1;
  fA = fmaxf(__uint_as_float((bitsA >> 9) | 0x3F800000u) - 1.0f, 1.1754943508222875e-38f);
  fB = fmaxf(__uint_as_float((bitsB >> 9) | 0x3F800000u) - 1.0f, 1.1754943508222875e-38f);
}

// ---------------- Kernel A: qkv = x @ qkv_w + b -> qb, kb (B,H,N,D bf16), vT (B,H,D,N bf16)
__global__ __launch_bounds__(256) void k_qkv(const float* __restrict__ x,
                                             const float* __restrict__ w,
                                             const float* __restrict__ bias,
                                             bf16* __restrict__ qb,
                                             bf16* __restrict__ kb,
                                             bf16* __restrict__ vTb){
  __shared__ float As[16][68];   // [k][m]
  __shared__ float Bs[16][68];   // [k][n]
  const int t  = threadIdx.x;
  const int tx = t & 15, ty = t >> 4;
  const int m0 = blockIdx.x * 64, n0 = blockIdx.y * 64;
  float c[4][4] = {};
  for (int k0 = 0; k0 < C_; k0 += 16){
    #pragma unroll
    for (int i = 0; i < 4; i++){
      int idx = t + 256*i;               // 1024 A elems: 64m x 16k
      int m = idx >> 4, k = idx & 15;
      As[k][m] = x[(size_t)(m0+m)*C_ + k0 + k];
      int n = idx & 63, k2 = idx >> 6;   // 1024 B elems: 16k x 64n
      Bs[k2][n] = w[(size_t)(k0+k2)*TC_ + n0 + n];
    }
    __syncthreads();
    #pragma unroll
    for (int k = 0; k < 16; k++){
      float av[4], bv[4];
      #pragma unroll
      for (int i = 0; i < 4; i++) av[i] = As[k][ty*4+i];
      #pragma unroll
      for (int j = 0; j < 4; j++) bv[j] = Bs[k][tx*4+j];
      #pragma unroll
      for (int i = 0; i < 4; i++)
        #pragma unroll
        for (int j = 0; j < 4; j++) c[i][j] += av[i]*bv[j];
    }
    __syncthreads();
  }
  #pragma unroll
  for (int i = 0; i < 4; i++){
    int mg = m0 + ty*4 + i;
    int bb = mg >> 10, nn = mg & 1023;
    #pragma unroll
    for (int j = 0; j < 4; j++){
      int jg = n0 + tx*4 + j;
      int t3 = jg / C_;
      int rem = jg - t3*C_;
      int h = rem >> 6, d = rem & 63;
      bf16 val = __float2bfloat16(c[i][j] + bias[jg]);
      if (t3 == 0)      qb[((size_t)(bb*H_ + h)*N_ + nn)*D_ + d] = val;
      else if (t3 == 1) kb[((size_t)(bb*H_ + h)*N_ + nn)*D_ + d] = val;
      else              vTb[((size_t)(bb*H_ + h)*D_ + d)*N_ + nn] = val;
    }
  }
}

// ---------------- Kernel B (MFMA): scores[bh][n][m] = sum_d q[n,d]*k[m,d] -> f32 (attn region)
__global__ __launch_bounds__(256) void k_scores(const short* __restrict__ qb,
                                                const short* __restrict__ kb,
                                                float* __restrict__ qk){
  const int gw = blockIdx.x * 4 + (threadIdx.x >> 6);
  const int lane = threadIdx.x & 63;
  const int mt = gw & 63, nt = (gw >> 6) & 63, bh = gw >> 12;
  const int lo = lane & 15, quad = lane >> 4;
  const short* qrow = qb + ((size_t)bh*N_ + nt*16 + lo)*D_ + quad*8;
  const short* krow = kb + ((size_t)bh*N_ + mt*16 + lo)*D_ + quad*8;
  short8 a0 = *(const short8*)qrow;
  short8 b0 = *(const short8*)krow;
  short8 a1 = *(const short8*)(qrow + 32);
  short8 b1 = *(const short8*)(krow + 32);
  f32x4 acc = {0.f, 0.f, 0.f, 0.f};
  acc = __builtin_amdgcn_mfma_f32_16x16x32_bf16(a0, b0, acc, 0, 0, 0);
  acc = __builtin_amdgcn_mfma_f32_16x16x32_bf16(a1, b1, acc, 0, 0, 0);
  float* o = qk + (size_t)bh*N_*N_ + (size_t)(nt*16)*N_ + mt*16;
  #pragma unroll
  for (int r = 0; r < 4; r++)
    o[(size_t)(quad*4 + r)*N_ + lo] = acc[r];   // row=(lane>>4)*4+reg, col=lane&15
}

// ---------------- Kernel D (merged stats+softmax+conv+tanh+gumbel):
// one block per (b,n) row; handles all H=6 heads x 1024 m.
__global__ __launch_bounds__(256) void k_fuse(float* __restrict__ attn,    // in: scores, out: attn_mean
                                              const float* __restrict__ cw,
                                              const float* __restrict__ cb,
                                              float* __restrict__ u_out,
                                              unsigned long long* __restrict__ mbits,
                                              uint32_t g0k0, uint32_t g0k1,
                                              uint32_t g1k0, uint32_t g1k1){
  const int bn = blockIdx.x;                  // 0..4095
  const int bb = bn >> 10, n = bn & 1023;
  const int t = threadIdx.x, lane = t & 63, wid = t >> 6;
  __shared__ float redm[H_][4], reds[H_][4];

  float qv[H_][4];
  #pragma unroll
  for (int h = 0; h < H_; h++){
    const float* p = attn + (((size_t)(bb*H_ + h) << 10) + n) * N_;
    #pragma unroll
    for (int i = 0; i < 4; i++) qv[h][i] = p[t + 256*i];
  }
  // per-head max (wave shuffle + LDS cross-wave)
  #pragma unroll
  for (int h = 0; h < H_; h++){
    float mx = fmaxf(fmaxf(qv[h][0], qv[h][1]), fmaxf(qv[h][2], qv[h][3]));
    #pragma unroll
    for (int off = 32; off > 0; off >>= 1) mx = fmaxf(mx, __shfl_xor(mx, off));
    if (lane == 0) redm[h][wid] = mx;
  }
  __syncthreads();
  float mxh[H_], sm[H_];
  #pragma unroll
  for (int h = 0; h < H_; h++){
    mxh[h] = fmaxf(fmaxf(redm[h][0], redm[h][1]), fmaxf(redm[h][2], redm[h][3]));
    const float k2 = SCALE * LOG2E;
    float s = 0.f;
    #pragma unroll
    for (int i = 0; i < 4; i++) s += __builtin_amdgcn_exp2f((qv[h][i] - mxh[h]) * k2);
    #pragma unroll
    for (int off = 32; off > 0; off >>= 1) s += __shfl_xor(s, off);
    if (lane == 0) reds[h][wid] = s;
    sm[h] = s;
  }
  __syncthreads();
  float invS[H_];
  #pragma unroll
  for (int h = 0; h < H_; h++){
    float S = reds[h][0] + reds[h][1] + reds[h][2] + reds[h][3];
    invS[h] = __builtin_amdgcn_rcpf(S);
  }
  // write attn_mean (recompute exp)
  #pragma unroll
  for (int h = 0; h < H_; h++){
    float* p = attn + (((size_t)(bb*H_ + h) << 10) + n) * N_;
    const float k2 = SCALE * LOG2E;
    #pragma unroll
    for (int i = 0; i < 4; i++)
      p[t + 256*i] = __builtin_amdgcn_exp2f((qv[h][i] - mxh[h]) * k2) * invS[h];
  }
  // conv mix + u + gumbel hard bits
  // hard = (g1 - g0 > 2u-1). With L_i = log2(f_i) (both < 0) and t = 2u-1 = tanh(up):
  //   g1 - g0 = ln(L0/L1)  =>  hard <=> L0/L1 > e^t  <=>  L0 < L1 * e^t   (L1 < 0 flips)
  // This drops 2 of the 4 v_log_f32 per element vs the d-form (adds 1 exp2 + 1 mul).
  const uint32_t a2 = g0k0 ^ g0k1 ^ 0x1BD11BDAu;
  const uint32_t b2 = g1k0 ^ g1k1 ^ 0x1BD11BDAu;
  const uint32_t jrow = ((uint32_t)(bb*H_) << 20) | ((uint32_t)n << 10);
  #pragma unroll
  for (int i = 0; i < 4; i++){
    const uint32_t m = (uint32_t)(t + 256*i);
    #pragma unroll
    for (int o = 0; o < H_; o++){
      float up = cb[o];
      #pragma unroll
      for (int h = 0; h < H_; h++) up += cw[o*H_ + h] * qv[h][i];
      // u = (tanh(up)+1)/2 == sigmoid(2*up)
      float eneg = __builtin_amdgcn_exp2f(-2.0f * LOG2E * up);
      float uu   = __builtin_amdgcn_rcpf(1.0f + eneg);
      float tt   = 2.0f * uu - 1.0f;                      // tanh(up)
      float et   = __builtin_amdgcn_exp2f(tt * LOG2E);    // e^t
      uint32_t j = jrow + ((uint32_t)o << 20) + m;
      float f0, f1;
      tf_dual(j, g0k0, g0k1, a2, g1k0, g1k1, b2, f0, f1);
      float L0 = __builtin_amdgcn_logf(f0);               // log2(f0) <= 0
      float L1 = __builtin_amdgcn_logf(f1);
      int hard = L0 < L1 * et;
      u_out[(size_t)j] = uu;
      unsigned long long bal = __ballot(hard);
      if (lane == 0) mbits[(size_t)j >> 6] = bal;
    }
  }
}

// ---------------- Kernel E (MFMA): tmp[b,n,h,d] = sum_m (attn*mask)[bh,n,m] * v[bh,m,d]
// each wave: one 16-row n-tile x TWO 16-col d-tiles (attn read once for both)
__global__ __launch_bounds__(256) void k_av(const float* __restrict__ attn,
                                            const unsigned long long* __restrict__ mbits,
                                            const short* __restrict__ vTb,
                                            float* __restrict__ tmp){
  const int gw = blockIdx.x * 4 + (threadIdx.x >> 6);
  const int lane = threadIdx.x & 63;
  const int pr = gw & 1, nt = (gw >> 1) & 63, bh = gw >> 7;
  const int bb = bh / H_, h = bh - bb*H_;
  const int lo = lane & 15, quad = lane >> 4;
  const int row = nt*16 + lo;                       // n
  const float* arow = attn + ((size_t)bh*N_ + row)*N_ + quad*8;
  const unsigned long long* mrow = mbits + (((size_t)bh*N_ + row)*N_ >> 6);
  const short* vrow0 = vTb + ((size_t)bh*D_ + pr*32 + lo)*N_ + quad*8;
  const short* vrow1 = vrow0 + 16*N_;
  f32x4 acc0 = {0.f, 0.f, 0.f, 0.f};
  f32x4 acc1 = {0.f, 0.f, 0.f, 0.f};
  for (int m0 = 0; m0 < N_; m0 += 32){
    f32x4 av0 = *(const f32x4*)(arow + m0);
    f32x4 av1 = *(const f32x4*)(arow + m0 + 4);
    unsigned long long wb = mrow[(m0 + quad*8) >> 6];
    int base = (m0 + quad*8) & 63;
    float vals[8] = {av0[0], av0[1], av0[2], av0[3], av1[0], av1[1], av1[2], av1[3]};
    short8 a;
    #pragma unroll
    for (int j = 0; j < 8; j++)
      a[j] = f2bs(((wb >> (base + j)) & 1ull) ? vals[j] : 0.0f);
    short8 b0 = *(const short8*)(vrow0 + m0);
    short8 b1 = *(const short8*)(vrow1 + m0);
    acc0 = __builtin_amdgcn_mfma_f32_16x16x32_bf16(a, b0, acc0, 0, 0, 0);
    acc1 = __builtin_amdgcn_mfma_f32_16x16x32_bf16(a, b1, acc1, 0, 0, 0);
  }
  float* o = tmp + ((size_t)(bb*N_) + nt*16)*C_ + h*D_ + pr*32;
  #pragma unroll
  for (int r = 0; r < 4; r++){
    o[(size_t)(quad*4 + r)*C_ + lo]      = acc0[r];
    o[(size_t)(quad*4 + r)*C_ + 16 + lo] = acc1[r];
  }
}

// ---------------- Kernel F: out = tmp @ proj_w + proj_b (f32 out), 32x64 tiles
__global__ __launch_bounds__(256) void k_proj(const float* __restrict__ A,
                                              const float* __restrict__ w,
                                              const float* __restrict__ bias,
                                              float* __restrict__ out){
  __shared__ float As[16][36];   // [k][m] 32 rows
  __shared__ float Bs[16][68];   // [k][n] 64 cols
  const int t = threadIdx.x, tx = t & 15, ty = t >> 4;
  const int m0 = blockIdx.x * 32, n0 = blockIdx.y * 64;
  float c[2][4] = {};
  for (int k0 = 0; k0 < C_; k0 += 16){
    {
      int idx = t;                        // 512 A elems: 32m x 16k (2/thread)
      int m = idx >> 4, k = idx & 15;
      As[k][m] = A[(size_t)(m0+m)*C_ + k0 + k];
      idx = t + 256;
      m = idx >> 4; k = idx & 15;
      As[k][m] = A[(size_t)(m0+m)*C_ + k0 + k];
    }
    #pragma unroll
    for (int i = 0; i < 4; i++){
      int idx = t + 256*i;                // 1024 B elems: 16k x 64n
      int n = idx & 63, k2 = idx >> 6;
      Bs[k2][n] = w[(size_t)(k0+k2)*C_ + n0 + n];
    }
    __syncthreads();
    #pragma unroll
    for (int k = 0; k < 16; k++){
      float av[2], bv[4];
      #pragma unroll
      for (int i = 0; i < 2; i++) av[i] = As[k][ty*2+i];
      #pragma unroll
      for (int j = 0; j < 4; j++) bv[j] = Bs[k][tx*4+j];
      #pragma unroll
      for (int i = 0; i < 2; i++)
        #pragma unroll
        for (int j = 0; j < 4; j++) c[i][j] += av[i]*bv[j];
    }
    __syncthreads();
  }
  #pragma unroll
  for (int i = 0; i < 2; i++)
    #pragma unroll
    for (int j = 0; j < 4; j++)
      out[(size_t)(m0+ty*2+i)*C_ + n0+tx*4+j] = c[i][j] + bias[n0+tx*4+j];
}

extern "C" void kernel_launch(void* const* d_in, const int* in_sizes, int n_in,
                              void* d_out, int out_size, void* d_ws, size_t ws_size,
                              hipStream_t stream) {
  const float* x      = (const float*)d_in[0];
  const float* qkv_w  = (const float*)d_in[1];
  const float* qkv_b  = (const float*)d_in[2];
  const float* proj_w = (const float*)d_in[3];
  const float* proj_b = (const float*)d_in[4];
  const float* conv_w = (const float*)d_in[5];
  const float* conv_b = (const float*)d_in[6];

  float* out      = (float*)d_out;                      // B*N*C
  float* attn_out = out + (size_t)B_*N_*C_;             // B*H*N*N (scores then attn)
  float* u_out    = attn_out + (size_t)BHNN_;           // B*H*N*N

  // workspace layout (18.9 MB total; 28.5 MB proven safe)
  char* ws = (char*)d_ws;
  bf16* qb   = (bf16*)ws;                               // 3,145,728 B
  bf16* kb   = (bf16*)(ws + 3145728);                   // 3,145,728 B
  bf16* vTb  = (bf16*)(ws + 6291456);                   // 3,145,728 B
  unsigned long long* mbits = (unsigned long long*)(ws + 9437184); // 3,145,728 B
  float* tmp = (float*)(ws + 12582912);                 // 6,291,456 B

  // derived gumbel keys: fold_in(key(42)=(0,42), 0) and (.., 1)
  uint32_t g0k0, g0k1, g1k0, g1k1;
  { uint32_t a = 0u, b = 0u; tf2x32(0u, 42u, a, b); g0k0 = a; g0k1 = b; }
  { uint32_t a = 0u, b = 1u; tf2x32(0u, 42u, a, b); g1k0 = a; g1k1 = b; }

  dim3 blk(256);
  k_qkv   <<<dim3(64, 18),  blk, 0, stream>>>(x, qkv_w, qkv_b, qb, kb, vTb);
  k_scores<<<dim3(24576),   blk, 0, stream>>>((const short*)qb, (const short*)kb, attn_out);
  k_fuse  <<<dim3(4096),    blk, 0, stream>>>(attn_out, conv_w, conv_b,
                                              u_out, mbits,
                                              g0k0, g0k1, g1k0, g1k1);
  k_av    <<<dim3(768),     blk, 0, stream>>>(attn_out, mbits, (const short*)vTb, tmp);
  k_proj  <<<dim3(128, 6),  blk, 0, stream>>>(tmp, proj_w, proj_b, out);
}

// Round 2
// 466.325 us; speedup vs baseline: 1.0379x; 1.0322x over previous
//
#include <hip/hip_runtime.h>
#include <hip/hip_bf16.h>
#include <stdint.h>
#include <stddef.h>

#define B_ 4
#define N_ 1024
#define C_ 384
#define H_ 6
#define D_ 64
#define TC_ 1152          // 3*C
#define BHNN_ 25165824    // B*H*N*N
#define SCALE 0.125f
#define LOG2E 1.4426950408889634f
#define LN2 0.6931471805599453f

typedef __hip_bfloat16 bf16;
typedef __attribute__((ext_vector_type(2))) float f32x2;
typedef __attribute__((ext_vector_type(4))) float f32x4;
typedef __attribute__((ext_vector_type(8))) short short8;

union f4u { f32x4 v4; f32x2 v2[2]; };

__device__ __forceinline__ short f2bs(float x){
  bf16 b = __float2bfloat16(x);
  return *reinterpret_cast<short*>(&b);
}

// packed dual-FMA with src0 broadcast via op_sel (numerically = v_fma_f32 on both halves)
__device__ __forceinline__ void pk_fma_ll(f32x2& c, f32x2 a, f32x2 b){
  asm("v_pk_fma_f32 %0, %1, %2, %0 op_sel:[0,0,0] op_sel_hi:[0,1,1]" : "+v"(c) : "v"(a), "v"(b));
}
__device__ __forceinline__ void pk_fma_hh(f32x2& c, f32x2 a, f32x2 b){
  asm("v_pk_fma_f32 %0, %1, %2, %0 op_sel:[1,0,0] op_sel_hi:[1,1,1]" : "+v"(c) : "v"(a), "v"(b));
}

// ---------------- Threefry-2x32 (matches jax._src.prng) ----------------
#define TFR(x0,x1,r) { x0 += x1; x1 = ((x1)<<(r))|((x1)>>(32-(r))); x1 ^= x0; }

__host__ __device__ __forceinline__ void tf2x32(uint32_t k0, uint32_t k1,
                                                uint32_t& x0, uint32_t& x1){
  uint32_t k2 = k0 ^ k1 ^ 0x1BD11BDAu;
  x0 += k0; x1 += k1;
  TFR(x0,x1,13) TFR(x0,x1,15) TFR(x0,x1,26) TFR(x0,x1,6)
  x0 += k1; x1 += k2 + 1u;
  TFR(x0,x1,17) TFR(x0,x1,29) TFR(x0,x1,16) TFR(x0,x1,24)
  x0 += k2; x1 += k0 + 2u;
  TFR(x0,x1,13) TFR(x0,x1,15) TFR(x0,x1,26) TFR(x0,x1,6)
  x0 += k0; x1 += k1 + 3u;
  TFR(x0,x1,17) TFR(x0,x1,29) TFR(x0,x1,16) TFR(x0,x1,24)
  x0 += k1; x1 += k2 + 4u;
  TFR(x0,x1,13) TFR(x0,x1,15) TFR(x0,x1,26) TFR(x0,x1,6)
  x0 += k2; x1 += k0 + 5u;
}

__device__ __forceinline__ uint32_t rotl32(uint32_t x, uint32_t r){
#if __has_builtin(__builtin_amdgcn_alignbit)
  return __builtin_amdgcn_alignbit(x, x, 32u - r);
#else
  return (x << r) | (x >> (32u - r));
#endif
}

// dual-stream threefry: uniforms for BOTH gumbel keys at counter (0, j), 2-way ILP
__device__ __forceinline__ void tf_dual(uint32_t j,
    uint32_t ak0, uint32_t ak1, uint32_t ak2,
    uint32_t bk0, uint32_t bk1, uint32_t bk2,
    float& fA, float& fB){
  uint32_t x0 = ak0, x1 = j + ak1;
  uint32_t y0 = bk0, y1 = j + bk1;
  #define DTFR(r) { x0 += x1; y0 += y1;               \
                    x1 = rotl32(x1,(r)); y1 = rotl32(y1,(r)); \
                    x1 ^= x0; y1 ^= y0; }
  DTFR(13) DTFR(15) DTFR(26) DTFR(6)
  x0 += ak1; x1 += ak2 + 1u;  y0 += bk1; y1 += bk2 + 1u;
  DTFR(17) DTFR(29) DTFR(16) DTFR(24)
  x0 += ak2; x1 += ak0 + 2u;  y0 += bk2; y1 += bk0 + 2u;
  DTFR(13) DTFR(15) DTFR(26) DTFR(6)
  x0 += ak0; x1 += ak1 + 3u;  y0 += bk0; y1 += bk1 + 3u;
  DTFR(17) DTFR(29) DTFR(16) DTFR(24)
  x0 += ak1; x1 += ak2 + 4u;  y0 += bk1; y1 += bk2 + 4u;
  DTFR(13) DTFR(15) DTFR(26) DTFR(6)
  x0 += ak2; x1 += ak0 + 5u;  y0 += bk2; y1 += bk0 + 5u;
  #undef DTFR
  uint32_t bitsA = x0 ^ x1;
  uint32_t bitsB = y0 ^ y1;
  fA = fmaxf(__uint_as_float((bitsA >> 9) | 0x3F800000u) - 1.0f, 1.1754943508222875e-38f);
  fB = fmaxf(__uint_as_float((bitsB >> 9) | 0x3F800000u) - 1.0f, 1.1754943508222875e-38f);
}

// ---------------- Kernel A: qkv = x @ qkv_w + b -> qb, kb (B,H,N,D bf16), vT (B,H,D,N bf16)
// inner loop: 2x ds_read_b128 + 8x v_pk_fma_f32 (op_sel broadcast) = 32 FLOP / 10 slots
__global__ __launch_bounds__(256) void k_qkv(const float* __restrict__ x,
                                             const float* __restrict__ w,
                                             const float* __restrict__ bias,
                                             bf16* __restrict__ qb,
                                             bf16* __restrict__ kb,
                                             bf16* __restrict__ vTb){
  __shared__ __align__(16) float As[16][68];   // [k][m]
  __shared__ __align__(16) float Bs[16][68];   // [k][n]
  const int t  = threadIdx.x;
  const int tx = t & 15, ty = t >> 4;
  const int m0 = blockIdx.x * 64, n0 = blockIdx.y * 64;
  // staging maps (vectorized)
  const int am = t >> 2,        ak = (t & 3) * 4;   // A: f32x4 along k (transposed LDS write)
  const int bn = (t & 15) * 4,  bk = t >> 4;        // B: f32x4 along n (b128 LDS write)
  f32x2 c[4][2] = {};
  for (int k0 = 0; k0 < C_; k0 += 16){
    f32x4 av = *(const f32x4*)&x[(size_t)(m0+am)*C_ + k0 + ak];
    f32x4 bv = *(const f32x4*)&w[(size_t)(k0+bk)*TC_ + n0 + bn];
    __syncthreads();                 // previous iteration's readers done
    As[ak+0][am] = av[0]; As[ak+1][am] = av[1];
    As[ak+2][am] = av[2]; As[ak+3][am] = av[3];
    *(f32x4*)&Bs[bk][bn] = bv;
    __syncthreads();
    #pragma unroll
    for (int k = 0; k < 16; k++){
      f4u a, b;
      a.v4 = *(const f32x4*)&As[k][ty*4];
      b.v4 = *(const f32x4*)&Bs[k][tx*4];
      pk_fma_ll(c[0][0], a.v2[0], b.v2[0]); pk_fma_ll(c[0][1], a.v2[0], b.v2[1]);
      pk_fma_hh(c[1][0], a.v2[0], b.v2[0]); pk_fma_hh(c[1][1], a.v2[0], b.v2[1]);
      pk_fma_ll(c[2][0], a.v2[1], b.v2[0]); pk_fma_ll(c[2][1], a.v2[1], b.v2[1]);
      pk_fma_hh(c[3][0], a.v2[1], b.v2[0]); pk_fma_hh(c[3][1], a.v2[1], b.v2[1]);
    }
  }
  #pragma unroll
  for (int i = 0; i < 4; i++){
    int mg = m0 + ty*4 + i;
    int bb = mg >> 10, nn = mg & 1023;
    #pragma unroll
    for (int jp = 0; jp < 2; jp++){
      #pragma unroll
      for (int sub = 0; sub < 2; sub++){
        int jg = n0 + tx*4 + jp*2 + sub;
        int t3 = jg / C_;
        int rem = jg - t3*C_;
        int h = rem >> 6, d = rem & 63;
        bf16 val = __float2bfloat16(c[i][jp][sub] + bias[jg]);
        if (t3 == 0)      qb[((size_t)(bb*H_ + h)*N_ + nn)*D_ + d] = val;
        else if (t3 == 1) kb[((size_t)(bb*H_ + h)*N_ + nn)*D_ + d] = val;
        else              vTb[((size_t)(bb*H_ + h)*D_ + d)*N_ + nn] = val;
      }
    }
  }
}

// ---------------- Kernel B (MFMA): scores[bh][n][m] = sum_d q[n,d]*k[m,d] -> f32 (attn region)
__global__ __launch_bounds__(256) void k_scores(const short* __restrict__ qb,
                                                const short* __restrict__ kb,
                                                float* __restrict__ qk){
  const int gw = blockIdx.x * 4 + (threadIdx.x >> 6);
  const int lane = threadIdx.x & 63;
  const int mt = gw & 63, nt = (gw >> 6) & 63, bh = gw >> 12;
  const int lo = lane & 15, quad = lane >> 4;
  const short* qrow = qb + ((size_t)bh*N_ + nt*16 + lo)*D_ + quad*8;
  const short* krow = kb + ((size_t)bh*N_ + mt*16 + lo)*D_ + quad*8;
  short8 a0 = *(const short8*)qrow;
  short8 b0 = *(const short8*)krow;
  short8 a1 = *(const short8*)(qrow + 32);
  short8 b1 = *(const short8*)(krow + 32);
  f32x4 acc = {0.f, 0.f, 0.f, 0.f};
  acc = __builtin_amdgcn_mfma_f32_16x16x32_bf16(a0, b0, acc, 0, 0, 0);
  acc = __builtin_amdgcn_mfma_f32_16x16x32_bf16(a1, b1, acc, 0, 0, 0);
  float* o = qk + (size_t)bh*N_*N_ + (size_t)(nt*16)*N_ + mt*16;
  #pragma unroll
  for (int r = 0; r < 4; r++)
    o[(size_t)(quad*4 + r)*N_ + lo] = acc[r];   // row=(lane>>4)*4+reg, col=lane&15
}

// ---------------- Kernel D (merged stats+softmax+conv+tanh+gumbel):
// one block per (b,n) row; handles all H=6 heads x 1024 m.
__global__ __launch_bounds__(256) void k_fuse(float* __restrict__ attn,    // in: scores, out: attn_mean
                                              const float* __restrict__ cw,
                                              const float* __restrict__ cb,
                                              float* __restrict__ u_out,
                                              unsigned long long* __restrict__ mbits,
                                              uint32_t g0k0, uint32_t g0k1,
                                              uint32_t g1k0, uint32_t g1k1){
  const int bn = blockIdx.x;                  // 0..4095
  const int bb = bn >> 10, n = bn & 1023;
  const int t = threadIdx.x, lane = t & 63, wid = t >> 6;
  __shared__ float redm[H_][4], reds[H_][4];

  float qv[H_][4];
  #pragma unroll
  for (int h = 0; h < H_; h++){
    const float* p = attn + (((size_t)(bb*H_ + h) << 10) + n) * N_;
    #pragma unroll
    for (int i = 0; i < 4; i++) qv[h][i] = p[t + 256*i];
  }
  // per-head max (wave shuffle + LDS cross-wave)
  #pragma unroll
  for (int h = 0; h < H_; h++){
    float mx = fmaxf(fmaxf(qv[h][0], qv[h][1]), fmaxf(qv[h][2], qv[h][3]));
    #pragma unroll
    for (int off = 32; off > 0; off >>= 1) mx = fmaxf(mx, __shfl_xor(mx, off));
    if (lane == 0) redm[h][wid] = mx;
  }
  __syncthreads();
  // conv mix on RAW scores (before qv is overwritten with exp values)
  float up[H_][4];
  #pragma unroll
  for (int o = 0; o < H_; o++){
    float cbo = cb[o];
    #pragma unroll
    for (int i = 0; i < 4; i++) up[o][i] = cbo;
  }
  #pragma unroll
  for (int h = 0; h < H_; h++){
    #pragma unroll
    for (int o = 0; o < H_; o++){
      float wv = cw[o*H_ + h];
      #pragma unroll
      for (int i = 0; i < 4; i++) up[o][i] = fmaf(wv, qv[h][i], up[o][i]);
    }
  }
  // per-head sum; overwrite qv with its exp so the write pass reuses it
  float mxh[H_];
  #pragma unroll
  for (int h = 0; h < H_; h++){
    mxh[h] = fmaxf(fmaxf(redm[h][0], redm[h][1]), fmaxf(redm[h][2], redm[h][3]));
    const float k2 = SCALE * LOG2E;
    float s = 0.f;
    #pragma unroll
    for (int i = 0; i < 4; i++){
      float e = __builtin_amdgcn_exp2f((qv[h][i] - mxh[h]) * k2);
      qv[h][i] = e;
      s += e;
    }
    #pragma unroll
    for (int off = 32; off > 0; off >>= 1) s += __shfl_xor(s, off);
    if (lane == 0) reds[h][wid] = s;
  }
  __syncthreads();
  float invS[H_];
  #pragma unroll
  for (int h = 0; h < H_; h++){
    float S = reds[h][0] + reds[h][1] + reds[h][2] + reds[h][3];
    invS[h] = __builtin_amdgcn_rcpf(S);
  }
  // write attn_mean (exp reused from the sum pass — bit-identical)
  #pragma unroll
  for (int h = 0; h < H_; h++){
    float* p = attn + (((size_t)(bb*H_ + h) << 10) + n) * N_;
    #pragma unroll
    for (int i = 0; i < 4; i++)
      p[t + 256*i] = qv[h][i] * invS[h];
  }
  // gumbel hard bits:
  // hard = (g1 - g0 > 2u-1). With L_i = log2(f_i) (both < 0) and t = tanh(up):
  //   g1 - g0 = ln(L0/L1)  =>  hard <=> L0 < L1 * e^t   (L1 < 0 flips)
  const uint32_t a2k = g0k0 ^ g0k1 ^ 0x1BD11BDAu;
  const uint32_t b2k = g1k0 ^ g1k1 ^ 0x1BD11BDAu;
  const uint32_t jrow = ((uint32_t)(bb*H_) << 20) | ((uint32_t)n << 10);
  #pragma unroll
  for (int o = 0; o < H_; o++){
    float* uop = u_out + jrow + ((uint32_t)o << 20);             // uniform base -> saddr form
    unsigned long long* mbp = mbits + ((jrow + ((uint32_t)o << 20)) >> 6);
    #pragma unroll
    for (int i = 0; i < 4; i++){
      const uint32_t m = (uint32_t)(t + 256*i);
      float upv = up[o][i];
      float eneg = __builtin_amdgcn_exp2f(-2.0f * LOG2E * upv);
      float uu   = __builtin_amdgcn_rcpf(1.0f + eneg);
      float tt   = 2.0f * uu - 1.0f;                      // tanh(up)
      float et   = __builtin_amdgcn_exp2f(tt * LOG2E);    // e^t
      uint32_t j = jrow + ((uint32_t)o << 20) + m;
      float f0, f1;
      tf_dual(j, g0k0, g0k1, a2k, g1k0, g1k1, b2k, f0, f1);
      float L0 = __builtin_amdgcn_logf(f0);               // log2(f0) <= 0
      float L1 = __builtin_amdgcn_logf(f1);
      int hard = L0 < L1 * et;
      uop[m] = uu;
      unsigned long long bal = __ballot(hard);
      if (lane == 0) mbp[m >> 6] = bal;
    }
  }
}

// ---------------- Kernel E (MFMA): tmp[b,n,h,d] = sum_m (attn*mask)[bh,n,m] * v[bh,m,d]
__global__ __launch_bounds__(256) void k_av(const float* __restrict__ attn,
                                            const unsigned long long* __restrict__ mbits,
                                            const short* __restrict__ vTb,
                                            float* __restrict__ tmp){
  const int gw = blockIdx.x * 4 + (threadIdx.x >> 6);
  const int lane = threadIdx.x & 63;
  const int pr = gw & 1, nt = (gw >> 1) & 63, bh = gw >> 7;
  const int bb = bh / H_, h = bh - bb*H_;
  const int lo = lane & 15, quad = lane >> 4;
  const int row = nt*16 + lo;                       // n
  const float* arow = attn + ((size_t)bh*N_ + row)*N_ + quad*8;
  const unsigned long long* mrow = mbits + (((size_t)bh*N_ + row)*N_ >> 6);
  const short* vrow0 = vTb + ((size_t)bh*D_ + pr*32 + lo)*N_ + quad*8;
  const short* vrow1 = vrow0 + 16*N_;
  f32x4 acc0 = {0.f, 0.f, 0.f, 0.f};
  f32x4 acc1 = {0.f, 0.f, 0.f, 0.f};
  for (int m0 = 0; m0 < N_; m0 += 32){
    f32x4 av0 = *(const f32x4*)(arow + m0);
    f32x4 av1 = *(const f32x4*)(arow + m0 + 4);
    unsigned long long wb = mrow[(m0 + quad*8) >> 6];
    int base = (m0 + quad*8) & 63;
    float vals[8] = {av0[0], av0[1], av0[2], av0[3], av1[0], av1[1], av1[2], av1[3]};
    short8 a;
    #pragma unroll
    for (int j = 0; j < 8; j++)
      a[j] = f2bs(((wb >> (base + j)) & 1ull) ? vals[j] : 0.0f);
    short8 b0 = *(const short8*)(vrow0 + m0);
    short8 b1 = *(const short8*)(vrow1 + m0);
    acc0 = __builtin_amdgcn_mfma_f32_16x16x32_bf16(a, b0, acc0, 0, 0, 0);
    acc1 = __builtin_amdgcn_mfma_f32_16x16x32_bf16(a, b1, acc1, 0, 0, 0);
  }
  float* o = tmp + ((size_t)(bb*N_) + nt*16)*C_ + h*D_ + pr*32;
  #pragma unroll
  for (int r = 0; r < 4; r++){
    o[(size_t)(quad*4 + r)*C_ + lo]      = acc0[r];
    o[(size_t)(quad*4 + r)*C_ + 16 + lo] = acc1[r];
  }
}

// ---------------- Kernel F: out = tmp @ proj_w + proj_b (f32 out), 32x64 tiles, packed FMA
__global__ __launch_bounds__(256) void k_proj(const float* __restrict__ A,
                                              const float* __restrict__ w,
                                              const float* __restrict__ bias,
                                              float* __restrict__ out){
  __shared__ __align__(16) float As[16][36];   // [k][m] 32 rows
  __shared__ __align__(16) float Bs[16][68];   // [k][n] 64 cols
  const int t = threadIdx.x, tx = t & 15, ty = t >> 4;
  const int m0 = blockIdx.x * 32, n0 = blockIdx.y * 64;
  const int am = t >> 3,        ak = (t & 7) * 2;   // A: f32x2 along k
  const int bn = (t & 15) * 4,  bk = t >> 4;        // B: f32x4 along n
  f32x2 c[2][2] = {};
  for (int k0 = 0; k0 < C_; k0 += 16){
    f32x2 av = *(const f32x2*)&A[(size_t)(m0+am)*C_ + k0 + ak];
    f32x4 bv = *(const f32x4*)&w[(size_t)(k0+bk)*C_ + n0 + bn];
    __syncthreads();
    As[ak+0][am] = av[0]; As[ak+1][am] = av[1];
    *(f32x4*)&Bs[bk][bn] = bv;
    __syncthreads();
    #pragma unroll
    for (int k = 0; k < 16; k++){
      f32x2 a2 = *(const f32x2*)&As[k][ty*2];
      f4u b; b.v4 = *(const f32x4*)&Bs[k][tx*4];
      pk_fma_ll(c[0][0], a2, b.v2[0]); pk_fma_ll(c[0][1], a2, b.v2[1]);
      pk_fma_hh(c[1][0], a2, b.v2[0]); pk_fma_hh(c[1][1], a2, b.v2[1]);
    }
  }
  #pragma unroll
  for (int i = 0; i < 2; i++)
    #pragma unroll
    for (int jp = 0; jp < 2; jp++)
      #pragma unroll
      for (int sub = 0; sub < 2; sub++){
        int jg = n0 + tx*4 + jp*2 + sub;
        out[(size_t)(m0+ty*2+i)*C_ + jg] = c[i][jp][sub] + bias[jg];
      }
}

extern "C" void kernel_launch(void* const* d_in, const int* in_sizes, int n_in,
                              void* d_out, int out_size, void* d_ws, size_t ws_size,
                              hipStream_t stream) {
  const float* x      = (const float*)d_in[0];
  const float* qkv_w  = (const float*)d_in[1];
  const float* qkv_b  = (const float*)d_in[2];
  const float* proj_w = (const float*)d_in[3];
  const float* proj_b = (const float*)d_in[4];
  const float* conv_w = (const float*)d_in[5];
  const float* conv_b = (const float*)d_in[6];

  float* out      = (float*)d_out;                      // B*N*C
  float* attn_out = out + (size_t)B_*N_*C_;             // B*H*N*N (scores then attn)
  float* u_out    = attn_out + (size_t)BHNN_;           // B*H*N*N

  // workspace layout (18.9 MB total; 28.5 MB proven safe)
  char* ws = (char*)d_ws;
  bf16* qb   = (bf16*)ws;                               // 3,145,728 B
  bf16* kb   = (bf16*)(ws + 3145728);                   // 3,145,728 B
  bf16* vTb  = (bf16*)(ws + 6291456);                   // 3,145,728 B
  unsigned long long* mbits = (unsigned long long*)(ws + 9437184); // 3,145,728 B
  float* tmp = (float*)(ws + 12582912);                 // 6,291,456 B

  // derived gumbel keys: fold_in(key(42)=(0,42), 0) and (.., 1)
  uint32_t g0k0, g0k1, g1k0, g1k1;
  { uint32_t a = 0u, b = 0u; tf2x32(0u, 42u, a, b); g0k0 = a; g0k1 = b; }
  { uint32_t a = 0u, b = 1u; tf2x32(0u, 42u, a, b); g1k0 = a; g1k1 = b; }

  dim3 blk(256);
  k_qkv   <<<dim3(64, 18),  blk, 0, stream>>>(x, qkv_w, qkv_b, qb, kb, vTb);
  k_scores<<<dim3(24576),   blk, 0, stream>>>((const short*)qb, (const short*)kb, attn_out);
  k_fuse  <<<dim3(4096),    blk, 0, stream>>>(attn_out, conv_w, conv_b,
                                              u_out, mbits,
                                              g0k0, g0k1, g1k0, g1k1);
  k_av    <<<dim3(768),     blk, 0, stream>>>(attn_out, mbits, (const short*)vTb, tmp);
  k_proj  <<<dim3(128, 6),  blk, 0, stream>>>(tmp, proj_w, proj_b, out);
}